// Round 2
// baseline (205.201 us; speedup 1.0000x reference)
//
#include <hip/hip_runtime.h>
#include <cmath>

#define D_IN 1024
#define D_OUT 1024
#define NUM_HEADS 16
#define HEAD_DIM 64
#define BATCH 2
#define SEQ 2048
#define GK 1024
#define KT 32
#define NT_K (GK / 64)

typedef __attribute__((ext_vector_type(8))) short short8;
typedef __attribute__((ext_vector_type(4))) short short4v;
typedef __attribute__((ext_vector_type(4))) float float4v;
typedef __attribute__((ext_vector_type(16))) float f32x16;
typedef __attribute__((ext_vector_type(2))) int int2v;

__device__ __forceinline__ unsigned short f2bf(float f) {
  unsigned int u = __builtin_bit_cast(unsigned int, f);
  unsigned int r = (u + 0x7FFFu + ((u >> 16) & 1u)) >> 16;
  return (unsigned short)r;
}
__device__ __forceinline__ float bf2f(unsigned short h) {
  return __builtin_bit_cast(float, (unsigned int)h << 16);
}

// pack two f32 -> one dword of 2 bf16 (lo, hi), RNE
__device__ __forceinline__ unsigned int cvtpk(float lo, float hi) {
  unsigned int r;
  asm("v_cvt_pk_bf16_f32 %0, %1, %2" : "=v"(r) : "v"(lo), "v"(hi));
  return r;
}

// async global->LDS, 16 B per lane. lds base must be wave-uniform.
__device__ __forceinline__ void async_copy16(void* lds, const void* g) {
  __builtin_amdgcn_global_load_lds(
      (const __attribute__((address_space(1))) unsigned int*)g,
      (__attribute__((address_space(3))) unsigned int*)lds, 16, 0, 0);
}

// ---------------------------------------------------------------------------
// Fused pre-pass. z<4: transpose W (fp32 [K][N] -> bf16 [N][K]);
// z==4: convert x fp32 -> bf16 (16 elems/thread).
// ---------------------------------------------------------------------------
__global__ __launch_bounds__(256) void prep(
    const float* __restrict__ x, const float* __restrict__ Wq,
    const float* __restrict__ Wk, const float* __restrict__ Wv,
    const float* __restrict__ Wo, unsigned short* __restrict__ xb,
    unsigned short* __restrict__ wqkv_t, unsigned short* __restrict__ wo_t) {
  const int z = blockIdx.z;
  if (z == 4) {
    const int bid = blockIdx.y * 32 + blockIdx.x;  // 0..1023
    const size_t i0 = ((size_t)bid * 256 + threadIdx.x) * 16;
#pragma unroll
    for (int half = 0; half < 2; ++half) {
      const size_t o = i0 + half * 8;
      float4 a = *(const float4*)(x + o);
      float4 b = *(const float4*)(x + o + 4);
      union { unsigned short u[8]; short8 v; } t;
      t.u[0] = f2bf(a.x); t.u[1] = f2bf(a.y); t.u[2] = f2bf(a.z); t.u[3] = f2bf(a.w);
      t.u[4] = f2bf(b.x); t.u[5] = f2bf(b.y); t.u[6] = f2bf(b.z); t.u[7] = f2bf(b.w);
      *(short8*)(xb + o) = t.v;
    }
    return;
  }
  const float* W = (z == 0) ? Wq : (z == 1) ? Wk : (z == 2) ? Wv : Wo;
  unsigned short* out = (z < 3) ? (wqkv_t + (size_t)z * 1024 * 1024) : wo_t;

  __shared__ float T[32][33];
  const int r = threadIdx.x >> 3;
  const int c4 = (threadIdx.x & 7) << 2;
  const int k0 = blockIdx.x * 32, n0 = blockIdx.y * 32;

  float4 v = *(const float4*)(W + (size_t)(k0 + r) * 1024 + n0 + c4);
  T[r][c4 + 0] = v.x; T[r][c4 + 1] = v.y; T[r][c4 + 2] = v.z; T[r][c4 + 3] = v.w;
  __syncthreads();

  union { unsigned short u[4]; short4v v4; } o;
#pragma unroll
  for (int i = 0; i < 4; ++i) o.u[i] = f2bf(T[c4 + i][r]);
  *(short4v*)(out + (size_t)(n0 + r) * 1024 + k0 + c4) = o.v4;
}

// ---------------------------------------------------------------------------
// bf16 MFMA GEMM core, 128x128x64 tile, XOR-swizzled LDS staging (0 bank
// conflicts), double-buffered with prefetch-distance-1 (T3 minimum 2-phase):
// issue next-tile global_load_lds BEFORE computing current tile; single
// s_waitcnt vmcnt(0) + raw s_barrier per K-step (HBM latency overlaps MFMA).
// ---------------------------------------------------------------------------
__device__ __forceinline__ void stage_tile(
    const unsigned short* __restrict__ A, const unsigned short* __restrict__ Bt,
    unsigned short* As, unsigned short* Bs, int bufo, int bm, int bn, int k0,
    int wave, int lane) {
#pragma unroll
  for (int t = 0; t < 4; ++t) {
    const int c = (wave * 4 + t) * 64 + lane;
    const int srow = c >> 3;
    const int sgc = ((c & 7) ^ (srow & 7)) * 8;
    async_copy16(As + bufo + (size_t)c * 8,
                 A + (size_t)(bm + srow) * GK + k0 + sgc);
  }
#pragma unroll
  for (int t = 0; t < 4; ++t) {
    const int c = (wave * 4 + t) * 64 + lane;
    const int srow = c >> 3;
    const int sgc = ((c & 7) ^ (srow & 7)) * 8;
    async_copy16(Bs + bufo + (size_t)c * 8,
                 Bt + (size_t)(bn + srow) * GK + k0 + sgc);
  }
}

__device__ __forceinline__ void gemm_core(
    const unsigned short* __restrict__ A, const unsigned short* __restrict__ Bt,
    unsigned short* As, unsigned short* Bs, int bm, int bn, float4v acc[4][4]) {
  const int tid = threadIdx.x;
  const int wave = tid >> 6, lane = tid & 63;
  const int quad = lane >> 4, l16 = lane & 15;
  const int wr = wave >> 1, wc = wave & 1;
  const int sw = l16 & 7;

  // prologue: stage tile 0 into buf 0
  stage_tile(A, Bt, As, Bs, 0, bm, bn, 0, wave, lane);
  asm volatile("s_waitcnt vmcnt(0)" ::: "memory");
  __builtin_amdgcn_sched_barrier(0);
  __builtin_amdgcn_s_barrier();

  int cur = 0;
  for (int t = 0; t < NT_K; ++t) {
    // issue next-tile loads first (prefetch into the other buffer)
    if (t + 1 < NT_K)
      stage_tile(A, Bt, As, Bs, (cur ^ 1) * 8192, bm, bn, (t + 1) * 64, wave, lane);

    const unsigned short* Asc = As + cur * 8192;
    const unsigned short* Bsc = Bs + cur * 8192;
#pragma unroll
    for (int h = 0; h < 2; ++h) {
      short8 af[4], bfr[4];
#pragma unroll
      for (int i = 0; i < 4; ++i) {
        const int row = wr * 64 + i * 16 + l16;
        af[i] = *(const short8*)&Asc[((size_t)row * 8 + ((h * 4 + quad) ^ sw)) * 8];
      }
#pragma unroll
      for (int j = 0; j < 4; ++j) {
        const int row = wc * 64 + j * 16 + l16;
        bfr[j] = *(const short8*)&Bsc[((size_t)row * 8 + ((h * 4 + quad) ^ sw)) * 8];
      }
#pragma unroll
      for (int i = 0; i < 4; ++i)
#pragma unroll
        for (int j = 0; j < 4; ++j)
          acc[i][j] = __builtin_amdgcn_mfma_f32_16x16x32_bf16(af[i], bfr[j], acc[i][j], 0, 0, 0);
    }

    // next tile must be fully landed before anyone reads it
    asm volatile("s_waitcnt vmcnt(0)" ::: "memory");
    __builtin_amdgcn_sched_barrier(0);
    __builtin_amdgcn_s_barrier();
    cur ^= 1;
  }
}

// QKV GEMM: N = 3072 (Wq|Wk|Wv). Q pre-scaled by 0.125*log2(e), bhsd.
// K -> A-operand-blocked kblk (lane=key, hi=d-octet);
// V -> B-operand-blocked vblk (lane=d-col, hi=key-octet). 32x32x16 frags.
__global__ __launch_bounds__(256) void gemm_qkv(
    const unsigned short* __restrict__ A, const unsigned short* __restrict__ Bt,
    const float* __restrict__ bq, const float* __restrict__ bk,
    const float* __restrict__ bv,
    unsigned short* __restrict__ qbuf, unsigned short* __restrict__ kblk,
    unsigned short* __restrict__ vblk) {
  __shared__ unsigned short As[2 * 128 * 64];
  __shared__ unsigned short Bs[2 * 128 * 64];
  const int wave = threadIdx.x >> 6, lane = threadIdx.x & 63;
  const int quad = lane >> 4, l16 = lane & 15;
  const int wr = wave >> 1, wc = wave & 1;
  const int bm = blockIdx.x * 128, bn = blockIdx.y * 128;

  float4v acc[4][4] = {};
  gemm_core(A, Bt, As, Bs, bm, bn, acc);

#pragma unroll
  for (int j = 0; j < 4; ++j) {
    const int n = bn + wc * 64 + j * 16 + l16;
    const int seg = n >> 10, nn = n & 1023;
    const int h = nn >> 6, d = nn & 63;
    const float bsv = (seg == 0) ? bq[nn] : (seg == 1) ? bk[nn] : bv[nn];
    const float scale = (seg == 0) ? 0.18033688011112043f : 1.0f;  // 0.125*log2e
#pragma unroll
    for (int i = 0; i < 4; ++i) {
#pragma unroll
      for (int r = 0; r < 4; ++r) {
        const int m = bm + wr * 64 + i * 16 + quad * 4 + r;
        const int b = m >> 11, s = m & 2047;
        const int bh = b * NUM_HEADS + h;
        const unsigned short hv = f2bf((acc[i][j][r] + bsv) * scale);
        if (seg == 0) {
          qbuf[((size_t)bh * SEQ + s) * HEAD_DIM + d] = hv;
        } else if (seg == 1) {
          // frag f = d>>4 holds K[key = kt*32 + (lane&31)][d = f*16 + (lane>>5)*8 + j]
          kblk[((size_t)bh * 64 + (s >> 5)) * 2048 +
               (size_t)((d >> 4) * 512 + (((d >> 3) & 1) * 32 + (s & 31)) * 8 + (d & 7))] = hv;
        } else {
          // frag kk*2+dt holds V[key = kt*32 + kk*16 + (lane>>5)*8 + j][d = dt*32 + (lane&31)]
          vblk[((size_t)bh * 64 + (s >> 5)) * 2048 +
               (size_t)(((((s >> 4) & 1) * 2 + (d >> 5)) * 512) +
                        (((s >> 3) & 1) * 32 + (d & 31)) * 8 + (s & 7))] = hv;
        }
      }
    }
  }
}

// Output GEMM: N = 1024, fp32 out + bias.
__global__ __launch_bounds__(256) void gemm_out(
    const unsigned short* __restrict__ A, const unsigned short* __restrict__ Bt,
    const float* __restrict__ bo, float* __restrict__ out) {
  __shared__ unsigned short As[2 * 128 * 64];
  __shared__ unsigned short Bs[2 * 128 * 64];
  const int wave = threadIdx.x >> 6, lane = threadIdx.x & 63;
  const int quad = lane >> 4, l16 = lane & 15;
  const int wr = wave >> 1, wc = wave & 1;
  const int bm = blockIdx.x * 128, bn = blockIdx.y * 128;

  float4v acc[4][4] = {};
  gemm_core(A, Bt, As, Bs, bm, bn, acc);

#pragma unroll
  for (int j = 0; j < 4; ++j) {
    const int n = bn + wc * 64 + j * 16 + l16;
    const float bsv = bo[n];
#pragma unroll
    for (int i = 0; i < 4; ++i) {
#pragma unroll
      for (int r = 0; r < 4; ++r) {
        const int m = bm + wr * 64 + i * 16 + quad * 4 + r;
        out[(size_t)m * D_OUT + n] = acc[i][j][r] + bsv;
      }
    }
  }
}

// ---------------------------------------------------------------------------
// Flash attention, in-block split-K-4, swapped-QK^T 32x32 MFMA with fully
// in-register softmax (T12): mfma(K,Q) puts each lane's 16 P values on its
// own q-row (col=lane&31); cvt_pk_bf16 pairs + permlane32_swap redistribute
// keys into the PV A-fragment layout. No P LDS round-trip, no per-step DS
// traffic. Fixed-max exp2 partials are addable across waves; end-of-kernel
// in-LDS combine (single __syncthreads).
// ---------------------------------------------------------------------------
#define OBS 72  // OB row stride (shorts): 16B-aligned, bank-spread

__global__ __launch_bounds__(256) void attn_kernel(
    const unsigned short* __restrict__ qf, const unsigned short* __restrict__ kblk,
    const unsigned short* __restrict__ vblk, unsigned short* __restrict__ ctx) {
  __shared__ unsigned short OB[4 * 32 * OBS];  // per-wave partial O (18 KB)
  __shared__ float LL[4 * 32];                 // per-wave partial l

  const int id = blockIdx.x;
  const int bh = id & 31;                 // low bits -> XCD spread
  const int qblk = 63 - (id >> 5);        // long q-blocks first
  const int qw0 = qblk * 32;
  const int tid = threadIdx.x;
  const int w = tid >> 6;
  const int lane = tid & 63;
  const int l32 = lane & 31;
  const int hi = lane >> 5;

  const int nt = qblk + 1;                // total key tiles
  const int qch = (nt + 3) >> 2;
  const int t0 = w * qch;
  const int t1 = min(nt, t0 + qch);

  const size_t bh_base = (size_t)bh * SEQ * HEAD_DIM;
  const unsigned short* kb = kblk + bh_base + (size_t)lane * 8;
  const unsigned short* vb = vblk + bh_base + (size_t)lane * 8;

  // Q as 32x32x16 B-operand frags: col=lane&31=q-row, k=(lane>>5)*8+j
  short8 qfr[4];
  {
    const unsigned short* qrow =
        qf + bh_base + (size_t)(qw0 + l32) * HEAD_DIM + hi * 8;
#pragma unroll
    for (int f = 0; f < 4; ++f) qfr[f] = *(const short8*)(qrow + f * 16);
  }

  f32x16 O0 = {}, O1 = {};  // O[q = (reg&3)+8*(reg>>2)+4*hi][d = dt*32 + l32]
  float l_part = 0.f;

  if (t0 < t1) {
    short8 kA[4], vA[4], kB[4], vB[4];

    auto load = [&](int kt, short8 kd[4], short8 vd[4]) {
      const size_t base = (size_t)kt * 2048;
#pragma unroll
      for (int f = 0; f < 4; ++f) kd[f] = *(const short8*)(kb + base + f * 512);
#pragma unroll
      for (int f = 0; f < 4; ++f) vd[f] = *(const short8*)(vb + base + f * 512);
    };

    auto step = [&](int kt, const short8 kd[4], const short8 vd[4], bool masked) {
      (void)kt;
      // swapped QK^T: C[key = (reg&3)+8*(reg>>2)+4*hi][q = l32]
      f32x16 s = {};
#pragma unroll
      for (int f = 0; f < 4; ++f)
        s = __builtin_amdgcn_mfma_f32_32x32x16_bf16(kd[f], qfr[f], s, 0, 0, 0);

      float p[16];
#pragma unroll
      for (int g = 0; g < 4; ++g)
#pragma unroll
        for (int r = 0; r < 4; ++r) {
          float sv = s[g * 4 + r];
          if (masked) {
            const int krow = r + 8 * g + 4 * hi;  // diagonal tile: key<=q  <=>  krow<=l32
            sv = (krow <= l32) ? sv : -1e30f;
          }
          const float pv = __builtin_exp2f(sv);
          p[g * 4 + r] = pv;
          l_part += pv;
        }

      // c[g*2+t] holds keys {8g+4hi+2t, +1} for q=l32
      unsigned int c[8];
#pragma unroll
      for (int g = 0; g < 4; ++g) {
        c[g * 2 + 0] = cvtpk(p[g * 4 + 0], p[g * 4 + 1]);
        c[g * 2 + 1] = cvtpk(p[g * 4 + 2], p[g * 4 + 3]);
      }
      // permlane32_swap(a,b): a' = {a_lo, b_lo}, b' = {a_hi, b_hi}
      // pa[kk] dword t: keys kk*16 + hi*8 + {2t,2t+1}  (PV A-operand layout)
      {
        int2v r0 = __builtin_amdgcn_permlane32_swap((int)c[0], (int)c[2], false, false);
        c[0] = (unsigned int)r0.x; c[2] = (unsigned int)r0.y;
        int2v r1 = __builtin_amdgcn_permlane32_swap((int)c[1], (int)c[3], false, false);
        c[1] = (unsigned int)r1.x; c[3] = (unsigned int)r1.y;
        int2v r2 = __builtin_amdgcn_permlane32_swap((int)c[4], (int)c[6], false, false);
        c[4] = (unsigned int)r2.x; c[6] = (unsigned int)r2.y;
        int2v r3 = __builtin_amdgcn_permlane32_swap((int)c[5], (int)c[7], false, false);
        c[5] = (unsigned int)r3.x; c[7] = (unsigned int)r3.y;
      }
      union { unsigned int d[4]; short8 v; } pa0, pa1;
      pa0.d[0] = c[0]; pa0.d[1] = c[1]; pa0.d[2] = c[2]; pa0.d[3] = c[3];
      pa1.d[0] = c[4]; pa1.d[1] = c[5]; pa1.d[2] = c[6]; pa1.d[3] = c[7];

      // PV: O[dt] += pa[kk] x V[kk*2+dt]
      O0 = __builtin_amdgcn_mfma_f32_32x32x16_bf16(pa0.v, vd[0], O0, 0, 0, 0);
      O1 = __builtin_amdgcn_mfma_f32_32x32x16_bf16(pa0.v, vd[1], O1, 0, 0, 0);
      O0 = __builtin_amdgcn_mfma_f32_32x32x16_bf16(pa1.v, vd[2], O0, 0, 0, 0);
      O1 = __builtin_amdgcn_mfma_f32_32x32x16_bf16(pa1.v, vd[3], O1, 0, 0, 0);
    };

    load(t0, kA, vA);
    int kt = t0;
    while (true) {
      const bool lastA = (kt == t1 - 1);
      if (!lastA) load(kt + 1, kB, vB);
      step(kt, kA, vA, kt == nt - 1);
      if (lastA) break;
      ++kt;
      const bool lastB = (kt == t1 - 1);
      if (!lastB) load(kt + 1, kA, vA);
      step(kt, kB, vB, kt == nt - 1);
      if (lastB) break;
      ++kt;
    }
  }

  // ---- write this wave's partials to LDS ----
  // lane l and l+32 hold complementary keys of the same q-row
  const float lsum = l_part + __shfl_xor(l_part, 32);
  if (hi == 0) LL[w * 32 + l32] = lsum;
#pragma unroll
  for (int g = 0; g < 4; ++g)
#pragma unroll
    for (int r = 0; r < 4; ++r) {
      const int reg = g * 4 + r;
      const int row = r + 8 * g + 4 * hi;
      OB[(w * 32 + row) * OBS + l32] = f2bf(O0[reg]);
      OB[(w * 32 + row) * OBS + 32 + l32] = f2bf(O1[reg]);
    }

  __syncthreads();

  // ---- in-LDS combine: wave w handles rows w*8..w*8+7 ----
  const int row = w * 8 + (lane >> 3);
  const int col0 = (lane & 7) * 8;
  float acc[8] = {};
#pragma unroll
  for (int u = 0; u < 4; ++u) {
    const short8 t = *(const short8*)&OB[(u * 32 + row) * OBS + col0];
#pragma unroll
    for (int i = 0; i < 8; ++i) acc[i] += bf2f((unsigned short)t[i]);
  }
  const float inv = 1.0f / (LL[row] + LL[32 + row] + LL[64 + row] + LL[96 + row]);
  union { unsigned short u[8]; short8 v; } o;
#pragma unroll
  for (int i = 0; i < 8; ++i) o.u[i] = f2bf(acc[i] * inv);
  const int b = bh >> 4, h = bh & 15;
  const int qg = qw0 + row;
  *(short8*)(ctx + ((size_t)b * SEQ + qg) * D_OUT + h * HEAD_DIM + col0) = o.v;
}

// ---------------------------------------------------------------------------
extern "C" void kernel_launch(void* const* d_in, const int* in_sizes, int n_in,
                              void* d_out, int out_size, void* d_ws, size_t ws_size,
                              hipStream_t stream) {
  const float* x  = (const float*)d_in[0];
  const float* Wq = (const float*)d_in[1];
  const float* bq = (const float*)d_in[2];
  const float* Wk = (const float*)d_in[3];
  const float* bk = (const float*)d_in[4];
  const float* Wv = (const float*)d_in[5];
  const float* bv = (const float*)d_in[6];
  const float* Wo = (const float*)d_in[7];
  const float* bo = (const float*)d_in[8];
  float* out = (float*)d_out;

  const int M = BATCH * SEQ;  // 4096
  unsigned short* xb     = (unsigned short*)d_ws;                  // 8 MB
  unsigned short* wqkv_t = xb + (size_t)M * D_IN;                  // 6 MB
  unsigned short* wo_t   = wqkv_t + (size_t)3 * D_OUT * D_IN;      // 2 MB
  unsigned short* qb     = wo_t + (size_t)D_OUT * D_OUT;           // 8 MB
  unsigned short* kblk   = qb + (size_t)M * D_OUT;                 // 8 MB
  unsigned short* vblk   = kblk + (size_t)M * D_OUT;               // 8 MB
  unsigned short* cb     = vblk + (size_t)M * D_OUT;               // 8 MB

  prep<<<dim3(32, 32, 5), 256, 0, stream>>>(x, Wq, Wk, Wv, Wo, xb, wqkv_t, wo_t);
  gemm_qkv<<<dim3(M / 128, 3 * D_OUT / 128), 256, 0, stream>>>(
      xb, wqkv_t, bq, bk, bv, qb, kblk, vblk);
  attn_kernel<<<dim3(32 * 64), 256, 0, stream>>>(qb, kblk, vblk, cb);
  gemm_out<<<dim3(M / 128, D_OUT / 128), 256, 0, stream>>>(cb, wo_t, bo, out);
}

// Round 3
// 191.831 us; speedup vs baseline: 1.0697x; 1.0697x over previous
//
#include <hip/hip_runtime.h>
#include <cmath>

#define D_IN 1024
#define D_OUT 1024
#define NUM_HEADS 16
#define HEAD_DIM 64
#define BATCH 2
#define SEQ 2048
#define GK 1024
#define KT 32

typedef __attribute__((ext_vector_type(8))) short short8;
typedef __attribute__((ext_vector_type(4))) short short4v;
typedef __attribute__((ext_vector_type(4))) float float4v;
typedef __attribute__((ext_vector_type(16))) float f32x16;
typedef __attribute__((ext_vector_type(2))) int int2v;

__device__ __forceinline__ unsigned short f2bf(float f) {
  unsigned int u = __builtin_bit_cast(unsigned int, f);
  unsigned int r = (u + 0x7FFFu + ((u >> 16) & 1u)) >> 16;
  return (unsigned short)r;
}
__device__ __forceinline__ float bf2f(unsigned short h) {
  return __builtin_bit_cast(float, (unsigned int)h << 16);
}

// pack two f32 -> one dword of 2 bf16 (lo, hi), RNE
__device__ __forceinline__ unsigned int cvtpk(float lo, float hi) {
  unsigned int r;
  asm("v_cvt_pk_bf16_f32 %0, %1, %2" : "=v"(r) : "v"(lo), "v"(hi));
  return r;
}

// async global->LDS, 16 B per lane. lds base must be wave-uniform.
__device__ __forceinline__ void async_copy16(void* lds, const void* g) {
  __builtin_amdgcn_global_load_lds(
      (const __attribute__((address_space(1))) unsigned int*)g,
      (__attribute__((address_space(3))) unsigned int*)lds, 16, 0, 0);
}

// ---------------------------------------------------------------------------
// Fused pre-pass. z<4: transpose W (fp32 [K][N] -> bf16 [N][K]);
// z==4: convert x fp32 -> bf16 (16 elems/thread).
// ---------------------------------------------------------------------------
__global__ __launch_bounds__(256) void prep(
    const float* __restrict__ x, const float* __restrict__ Wq,
    const float* __restrict__ Wk, const float* __restrict__ Wv,
    const float* __restrict__ Wo, unsigned short* __restrict__ xb,
    unsigned short* __restrict__ wqkv_t, unsigned short* __restrict__ wo_t) {
  const int z = blockIdx.z;
  if (z == 4) {
    const int bid = blockIdx.y * 32 + blockIdx.x;  // 0..1023
    const size_t i0 = ((size_t)bid * 256 + threadIdx.x) * 16;
#pragma unroll
    for (int half = 0; half < 2; ++half) {
      const size_t o = i0 + half * 8;
      float4 a = *(const float4*)(x + o);
      float4 b = *(const float4*)(x + o + 4);
      union { unsigned short u[8]; short8 v; } t;
      t.u[0] = f2bf(a.x); t.u[1] = f2bf(a.y); t.u[2] = f2bf(a.z); t.u[3] = f2bf(a.w);
      t.u[4] = f2bf(b.x); t.u[5] = f2bf(b.y); t.u[6] = f2bf(b.z); t.u[7] = f2bf(b.w);
      *(short8*)(xb + o) = t.v;
    }
    return;
  }
  const float* W = (z == 0) ? Wq : (z == 1) ? Wk : (z == 2) ? Wv : Wo;
  unsigned short* out = (z < 3) ? (wqkv_t + (size_t)z * 1024 * 1024) : wo_t;

  __shared__ float T[32][33];
  const int r = threadIdx.x >> 3;
  const int c4 = (threadIdx.x & 7) << 2;
  const int k0 = blockIdx.x * 32, n0 = blockIdx.y * 32;

  float4 v = *(const float4*)(W + (size_t)(k0 + r) * 1024 + n0 + c4);
  T[r][c4 + 0] = v.x; T[r][c4 + 1] = v.y; T[r][c4 + 2] = v.z; T[r][c4 + 3] = v.w;
  __syncthreads();

  union { unsigned short u[4]; short4v v4; } o;
#pragma unroll
  for (int i = 0; i < 4; ++i) o.u[i] = f2bf(T[c4 + i][r]);
  *(short4v*)(out + (size_t)(n0 + r) * 1024 + k0 + c4) = o.v4;
}

// ---------------------------------------------------------------------------
// bf16 MFMA GEMM core, 128x128x64 tile, XOR-swizzled LDS staging (0 bank
// conflicts). Single-buffered m97 structure (r1-proven: implicit wave-level
// overlap at 4-5 blocks/CU beats explicit dbuf which halves occupancy).
// ---------------------------------------------------------------------------
__device__ __forceinline__ void gemm_core(
    const unsigned short* __restrict__ A, const unsigned short* __restrict__ Bt,
    unsigned short* As, unsigned short* Bs, int bm, int bn, float4v acc[4][4]) {
  const int tid = threadIdx.x;
  const int wave = tid >> 6, lane = tid & 63;
  const int quad = lane >> 4, l16 = lane & 15;
  const int wr = wave >> 1, wc = wave & 1;
  const int sw = l16 & 7;

  int srow[4], sgc[4];
#pragma unroll
  for (int t = 0; t < 4; ++t) {
    const int c = (wave * 4 + t) * 64 + lane;
    srow[t] = c >> 3;
    sgc[t] = ((c & 7) ^ (srow[t] & 7)) * 8;
  }

  for (int k0 = 0; k0 < GK; k0 += 64) {
    __syncthreads();
#pragma unroll
    for (int t = 0; t < 4; ++t) {
      const int c = (wave * 4 + t) * 64 + lane;
      async_copy16(As + (size_t)c * 8, A + (size_t)(bm + srow[t]) * GK + k0 + sgc[t]);
    }
#pragma unroll
    for (int t = 0; t < 4; ++t) {
      const int c = (wave * 4 + t) * 64 + lane;
      async_copy16(Bs + (size_t)c * 8, Bt + (size_t)(bn + srow[t]) * GK + k0 + sgc[t]);
    }
    __syncthreads();

#pragma unroll
    for (int h = 0; h < 2; ++h) {
      short8 af[4], bfr[4];
#pragma unroll
      for (int i = 0; i < 4; ++i) {
        const int row = wr * 64 + i * 16 + l16;
        af[i] = *(const short8*)&As[((size_t)row * 8 + ((h * 4 + quad) ^ sw)) * 8];
      }
#pragma unroll
      for (int j = 0; j < 4; ++j) {
        const int row = wc * 64 + j * 16 + l16;
        bfr[j] = *(const short8*)&Bs[((size_t)row * 8 + ((h * 4 + quad) ^ sw)) * 8];
      }
#pragma unroll
      for (int i = 0; i < 4; ++i)
#pragma unroll
        for (int j = 0; j < 4; ++j)
          acc[i][j] = __builtin_amdgcn_mfma_f32_16x16x32_bf16(af[i], bfr[j], acc[i][j], 0, 0, 0);
    }
  }
}

// QKV GEMM: N = 3072 (Wq|Wk|Wv). Q pre-scaled by 0.125*log2(e), bhsd.
// Epilogue routes the C tile through LDS (bias+scale+bf16 applied at write)
// so every global store is a fully-coalesced 1KB/wave short8 chunk of the
// fragment-blocked kblk/vblk (and qbuf) layouts. Replaces 48 scattered 2B
// stores/thread with 8 coalesced short8 stores/thread.
__global__ __launch_bounds__(256) void gemm_qkv(
    const unsigned short* __restrict__ A, const unsigned short* __restrict__ Bt,
    const float* __restrict__ bq, const float* __restrict__ bk,
    const float* __restrict__ bv,
    unsigned short* __restrict__ qbuf, unsigned short* __restrict__ kblk,
    unsigned short* __restrict__ vblk) {
  // staging (first 16384 shorts) and epilogue C-tile (128 x stride-136)
  // time-share one buffer: 128*136 = 17408 shorts = 34816 B.
  __shared__ unsigned short SMEM[128 * 136];
  const int tid = threadIdx.x;
  const int wave = tid >> 6, lane = tid & 63;
  const int quad = lane >> 4, l16 = lane & 15;
  const int wr = wave >> 1, wc = wave & 1;
  const int bm = blockIdx.x * 128, bn = blockIdx.y * 128;

  float4v acc[4][4] = {};
  gemm_core(A, Bt, SMEM, SMEM + 8192, bm, bn, acc);

  __syncthreads();  // all waves done reading staging LDS

  const int seg = bn >> 10;        // 0=Q 1=K 2=V (block fully inside one seg)
  const int nb0 = bn & 1023;
  const float* bias = (seg == 0) ? bq : (seg == 1) ? bk : bv;
  const float scale = (seg == 0) ? 0.18033688011112043f : 1.0f;  // 0.125*log2e

  // C fragments -> LDS [m][n], stride 136 shorts (272 B: 16B-aligned rows,
  // bank-spread columns).
#pragma unroll
  for (int j = 0; j < 4; ++j) {
    const int nl = wc * 64 + j * 16 + l16;
    const float bsv = bias[nb0 + nl];
#pragma unroll
    for (int i = 0; i < 4; ++i) {
#pragma unroll
      for (int r = 0; r < 4; ++r) {
        const int ml = wr * 64 + i * 16 + quad * 4 + r;
        SMEM[ml * 136 + nl] = f2bf((acc[i][j][r] + bsv) * scale);
      }
    }
  }
  __syncthreads();

  const int b = bm >> 11;       // batch (block fully inside one batch)
  const int s0 = bm & 2047;     // seq base

  if (seg == 0) {
    // qbuf[(bh*SEQ+s)*64 + d]
#pragma unroll
    for (int it = 0; it < 8; ++it) {
      const int linear = it * 256 + tid;
      const int d3 = linear & 7;              // d-octet
      const int sl = (linear >> 3) & 127;     // local seq row
      const int h = linear >> 10;             // head within block (0..1)
      const short8 vv = *(const short8*)&SMEM[sl * 136 + h * 64 + d3 * 8];
      const int bh = b * NUM_HEADS + (nb0 >> 6) + h;
      *(short8*)&qbuf[((size_t)bh * SEQ + s0 + sl) * HEAD_DIM + d3 * 8] = vv;
    }
  } else if (seg == 1) {
    // kblk tile idx: f*512 + hb*256 + key*8 + d0  (f=d>>4, hb=(d>>3)&1)
#pragma unroll
    for (int it = 0; it < 8; ++it) {
      const int linear = it * 256 + tid;
      const int key = linear & 31;
      const int hb = (linear >> 5) & 1;
      const int f = (linear >> 6) & 3;
      const int st = (linear >> 8) & 3;       // 32-key sub-tile within block
      const int h = linear >> 10;
      const int ml = st * 32 + key;
      const int nl = h * 64 + f * 16 + hb * 8;
      const short8 vv = *(const short8*)&SMEM[ml * 136 + nl];
      const int bh = b * NUM_HEADS + (nb0 >> 6) + h;
      const int stg = (s0 >> 5) + st;
      *(short8*)&kblk[((size_t)bh * 64 + stg) * 2048 + f * 512 + hb * 256 + key * 8] = vv;
    }
  } else {
    // vblk tile idx: (kk*2+dt)*512 + s8*256 + d31*8 + s0i
#pragma unroll
    for (int it = 0; it < 8; ++it) {
      const int linear = it * 256 + tid;
      const int d31 = linear & 31;
      const int s8 = (linear >> 5) & 1;
      const int dt = (linear >> 6) & 1;
      const int kk = (linear >> 7) & 1;
      const int st = (linear >> 8) & 3;
      const int h = linear >> 10;
      const int nl = h * 64 + dt * 32 + d31;
      const int mlb = st * 32 + kk * 16 + s8 * 8;
      union { unsigned short u[8]; short8 v; } vv;
#pragma unroll
      for (int s0i = 0; s0i < 8; ++s0i)
        vv.u[s0i] = SMEM[(mlb + s0i) * 136 + nl];
      const int bh = b * NUM_HEADS + (nb0 >> 6) + h;
      const int stg = (s0 >> 5) + st;
      *(short8*)&vblk[((size_t)bh * 64 + stg) * 2048 + (kk * 2 + dt) * 512 +
                      s8 * 256 + d31 * 8] = vv.v;
    }
  }
}

// Output GEMM: N = 1024, fp32 out + bias.
__global__ __launch_bounds__(256) void gemm_out(
    const unsigned short* __restrict__ A, const unsigned short* __restrict__ Bt,
    const float* __restrict__ bo, float* __restrict__ out) {
  __shared__ unsigned short As[128 * 64];
  __shared__ unsigned short Bs[128 * 64];
  const int wave = threadIdx.x >> 6, lane = threadIdx.x & 63;
  const int quad = lane >> 4, l16 = lane & 15;
  const int wr = wave >> 1, wc = wave & 1;
  const int bm = blockIdx.x * 128, bn = blockIdx.y * 128;

  float4v acc[4][4] = {};
  gemm_core(A, Bt, As, Bs, bm, bn, acc);

#pragma unroll
  for (int j = 0; j < 4; ++j) {
    const int n = bn + wc * 64 + j * 16 + l16;
    const float bsv = bo[n];
#pragma unroll
    for (int i = 0; i < 4; ++i) {
#pragma unroll
      for (int r = 0; r < 4; ++r) {
        const int m = bm + wr * 64 + i * 16 + quad * 4 + r;
        out[(size_t)m * D_OUT + n] = acc[i][j][r] + bsv;
      }
    }
  }
}

// ---------------------------------------------------------------------------
// Flash attention, in-block split-K-4, swapped-QK^T 32x32 MFMA with fully
// in-register softmax (T12): mfma(K,Q) puts each lane's 16 P values on its
// own q-row (col=lane&31); cvt_pk_bf16 pairs + permlane32_swap redistribute
// keys into the PV A-fragment layout. No P LDS round-trip, no per-step DS
// traffic. Fixed-max exp2 partials are addable across waves; end-of-kernel
// in-LDS combine (single __syncthreads).
// ---------------------------------------------------------------------------
#define OBS 72  // OB row stride (shorts): 16B-aligned, bank-spread

__global__ __launch_bounds__(256) void attn_kernel(
    const unsigned short* __restrict__ qf, const unsigned short* __restrict__ kblk,
    const unsigned short* __restrict__ vblk, unsigned short* __restrict__ ctx) {
  __shared__ unsigned short OB[4 * 32 * OBS];  // per-wave partial O (18 KB)
  __shared__ float LL[4 * 32];                 // per-wave partial l

  const int id = blockIdx.x;
  const int bh = id & 31;                 // low bits -> XCD spread
  const int qblk = 63 - (id >> 5);        // long q-blocks first
  const int qw0 = qblk * 32;
  const int tid = threadIdx.x;
  const int w = tid >> 6;
  const int lane = tid & 63;
  const int l32 = lane & 31;
  const int hi = lane >> 5;

  const int nt = qblk + 1;                // total key tiles
  const int qch = (nt + 3) >> 2;
  const int t0 = w * qch;
  const int t1 = min(nt, t0 + qch);

  const size_t bh_base = (size_t)bh * SEQ * HEAD_DIM;
  const unsigned short* kb = kblk + bh_base + (size_t)lane * 8;
  const unsigned short* vb = vblk + bh_base + (size_t)lane * 8;

  // Q as 32x32x16 B-operand frags: col=lane&31=q-row, k=(lane>>5)*8+j
  short8 qfr[4];
  {
    const unsigned short* qrow =
        qf + bh_base + (size_t)(qw0 + l32) * HEAD_DIM + hi * 8;
#pragma unroll
    for (int f = 0; f < 4; ++f) qfr[f] = *(const short8*)(qrow + f * 16);
  }

  f32x16 O0 = {}, O1 = {};  // O[q = (reg&3)+8*(reg>>2)+4*hi][d = dt*32 + l32]
  float l_part = 0.f;

  if (t0 < t1) {
    short8 kA[4], vA[4], kB[4], vB[4];

    auto load = [&](int kt, short8 kd[4], short8 vd[4]) {
      const size_t base = (size_t)kt * 2048;
#pragma unroll
      for (int f = 0; f < 4; ++f) kd[f] = *(const short8*)(kb + base + f * 512);
#pragma unroll
      for (int f = 0; f < 4; ++f) vd[f] = *(const short8*)(vb + base + f * 512);
    };

    auto step = [&](int kt, const short8 kd[4], const short8 vd[4], bool masked) {
      (void)kt;
      // swapped QK^T: C[key = (reg&3)+8*(reg>>2)+4*hi][q = l32]
      f32x16 s = {};
#pragma unroll
      for (int f = 0; f < 4; ++f)
        s = __builtin_amdgcn_mfma_f32_32x32x16_bf16(kd[f], qfr[f], s, 0, 0, 0);

      float p[16];
#pragma unroll
      for (int g = 0; g < 4; ++g)
#pragma unroll
        for (int r = 0; r < 4; ++r) {
          float sv = s[g * 4 + r];
          if (masked) {
            const int krow = r + 8 * g + 4 * hi;  // diagonal tile: key<=q  <=>  krow<=l32
            sv = (krow <= l32) ? sv : -1e30f;
          }
          const float pv = __builtin_exp2f(sv);
          p[g * 4 + r] = pv;
          l_part += pv;
        }

      // c[g*2+t] holds keys {8g+4hi+2t, +1} for q=l32
      unsigned int c[8];
#pragma unroll
      for (int g = 0; g < 4; ++g) {
        c[g * 2 + 0] = cvtpk(p[g * 4 + 0], p[g * 4 + 1]);
        c[g * 2 + 1] = cvtpk(p[g * 4 + 2], p[g * 4 + 3]);
      }
      // permlane32_swap(a,b): a' = {a_lo, b_lo}, b' = {a_hi, b_hi}
      // pa[kk] dword t: keys kk*16 + hi*8 + {2t,2t+1}  (PV A-operand layout)
      {
        int2v r0 = __builtin_amdgcn_permlane32_swap((int)c[0], (int)c[2], false, false);
        c[0] = (unsigned int)r0.x; c[2] = (unsigned int)r0.y;
        int2v r1 = __builtin_amdgcn_permlane32_swap((int)c[1], (int)c[3], false, false);
        c[1] = (unsigned int)r1.x; c[3] = (unsigned int)r1.y;
        int2v r2 = __builtin_amdgcn_permlane32_swap((int)c[4], (int)c[6], false, false);
        c[4] = (unsigned int)r2.x; c[6] = (unsigned int)r2.y;
        int2v r3 = __builtin_amdgcn_permlane32_swap((int)c[5], (int)c[7], false, false);
        c[5] = (unsigned int)r3.x; c[7] = (unsigned int)r3.y;
      }
      union { unsigned int d[4]; short8 v; } pa0, pa1;
      pa0.d[0] = c[0]; pa0.d[1] = c[1]; pa0.d[2] = c[2]; pa0.d[3] = c[3];
      pa1.d[0] = c[4]; pa1.d[1] = c[5]; pa1.d[2] = c[6]; pa1.d[3] = c[7];

      // PV: O[dt] += pa[kk] x V[kk*2+dt]
      O0 = __builtin_amdgcn_mfma_f32_32x32x16_bf16(pa0.v, vd[0], O0, 0, 0, 0);
      O1 = __builtin_amdgcn_mfma_f32_32x32x16_bf16(pa0.v, vd[1], O1, 0, 0, 0);
      O0 = __builtin_amdgcn_mfma_f32_32x32x16_bf16(pa1.v, vd[2], O0, 0, 0, 0);
      O1 = __builtin_amdgcn_mfma_f32_32x32x16_bf16(pa1.v, vd[3], O1, 0, 0, 0);
    };

    load(t0, kA, vA);
    int kt = t0;
    while (true) {
      const bool lastA = (kt == t1 - 1);
      if (!lastA) load(kt + 1, kB, vB);
      step(kt, kA, vA, kt == nt - 1);
      if (lastA) break;
      ++kt;
      const bool lastB = (kt == t1 - 1);
      if (!lastB) load(kt + 1, kA, vA);
      step(kt, kB, vB, kt == nt - 1);
      if (lastB) break;
      ++kt;
    }
  }

  // ---- write this wave's partials to LDS ----
  // lane l and l+32 hold complementary keys of the same q-row
  const float lsum = l_part + __shfl_xor(l_part, 32);
  if (hi == 0) LL[w * 32 + l32] = lsum;
#pragma unroll
  for (int g = 0; g < 4; ++g)
#pragma unroll
    for (int r = 0; r < 4; ++r) {
      const int reg = g * 4 + r;
      const int row = r + 8 * g + 4 * hi;
      OB[(w * 32 + row) * OBS + l32] = f2bf(O0[reg]);
      OB[(w * 32 + row) * OBS + 32 + l32] = f2bf(O1[reg]);
    }

  __syncthreads();

  // ---- in-LDS combine: wave w handles rows w*8..w*8+7 ----
  const int row = w * 8 + (lane >> 3);
  const int col0 = (lane & 7) * 8;
  float acc[8] = {};
#pragma unroll
  for (int u = 0; u < 4; ++u) {
    const short8 t = *(const short8*)&OB[(u * 32 + row) * OBS + col0];
#pragma unroll
    for (int i = 0; i < 8; ++i) acc[i] += bf2f((unsigned short)t[i]);
  }
  const float inv = 1.0f / (LL[row] + LL[32 + row] + LL[64 + row] + LL[96 + row]);
  union { unsigned short u[8]; short8 v; } o;
#pragma unroll
  for (int i = 0; i < 8; ++i) o.u[i] = f2bf(acc[i] * inv);
  const int b = bh >> 4, h = bh & 15;
  const int qg = qw0 + row;
  *(short8*)(ctx + ((size_t)b * SEQ + qg) * D_OUT + h * HEAD_DIM + col0) = o.v;
}

// ---------------------------------------------------------------------------
extern "C" void kernel_launch(void* const* d_in, const int* in_sizes, int n_in,
                              void* d_out, int out_size, void* d_ws, size_t ws_size,
                              hipStream_t stream) {
  const float* x  = (const float*)d_in[0];
  const float* Wq = (const float*)d_in[1];
  const float* bq = (const float*)d_in[2];
  const float* Wk = (const float*)d_in[3];
  const float* bk = (const float*)d_in[4];
  const float* Wv = (const float*)d_in[5];
  const float* bv = (const float*)d_in[6];
  const float* Wo = (const float*)d_in[7];
  const float* bo = (const float*)d_in[8];
  float* out = (float*)d_out;

  const int M = BATCH * SEQ;  // 4096
  unsigned short* xb     = (unsigned short*)d_ws;                  // 8 MB
  unsigned short* wqkv_t = xb + (size_t)M * D_IN;                  // 6 MB
  unsigned short* wo_t   = wqkv_t + (size_t)3 * D_OUT * D_IN;      // 2 MB
  unsigned short* qb     = wo_t + (size_t)D_OUT * D_OUT;           // 8 MB
  unsigned short* kblk   = qb + (size_t)M * D_OUT;                 // 8 MB
  unsigned short* vblk   = kblk + (size_t)M * D_OUT;               // 8 MB
  unsigned short* cb     = vblk + (size_t)M * D_OUT;               // 8 MB

  prep<<<dim3(32, 32, 5), 256, 0, stream>>>(x, Wq, Wk, Wv, Wo, xb, wqkv_t, wo_t);
  gemm_qkv<<<dim3(M / 128, 3 * D_OUT / 128), 256, 0, stream>>>(
      xb, wqkv_t, bq, bk, bv, qb, kblk, vblk);
  attn_kernel<<<dim3(32 * 64), 256, 0, stream>>>(qb, kblk, vblk, cb);
  gemm_out<<<dim3(M / 128, D_OUT / 128), 256, 0, stream>>>(cb, wo_t, bo, out);
}

// Round 4
// 178.459 us; speedup vs baseline: 1.1498x; 1.0749x over previous
//
#include <hip/hip_runtime.h>
#include <cmath>

#define D_IN 1024
#define D_OUT 1024
#define NUM_HEADS 16
#define HEAD_DIM 64
#define BATCH 2
#define SEQ 2048
#define GK 1024
#define KT 32
#define NT_K (GK / 64)

typedef __attribute__((ext_vector_type(8))) short short8;
typedef __attribute__((ext_vector_type(4))) short short4v;
typedef __attribute__((ext_vector_type(4))) float float4v;
typedef __attribute__((ext_vector_type(16))) float f32x16;
typedef __attribute__((ext_vector_type(2))) int int2v;

__device__ __forceinline__ unsigned short f2bf(float f) {
  unsigned int u = __builtin_bit_cast(unsigned int, f);
  unsigned int r = (u + 0x7FFFu + ((u >> 16) & 1u)) >> 16;
  return (unsigned short)r;
}
__device__ __forceinline__ float bf2f(unsigned short h) {
  return __builtin_bit_cast(float, (unsigned int)h << 16);
}

// pack two f32 -> one dword of 2 bf16 (lo, hi), RNE
__device__ __forceinline__ unsigned int cvtpk(float lo, float hi) {
  unsigned int r;
  asm("v_cvt_pk_bf16_f32 %0, %1, %2" : "=v"(r) : "v"(lo), "v"(hi));
  return r;
}

// async global->LDS, 16 B per lane. lds base must be wave-uniform.
__device__ __forceinline__ void async_copy16(void* lds, const void* g) {
  __builtin_amdgcn_global_load_lds(
      (const __attribute__((address_space(1))) unsigned int*)g,
      (__attribute__((address_space(3))) unsigned int*)lds, 16, 0, 0);
}

// ---------------------------------------------------------------------------
// Fused pre-pass. z<4: transpose W (fp32 [K][N] -> bf16 [N][K]);
// z==4: convert x fp32 -> bf16 (16 elems/thread, cvt_pk packed).
// ---------------------------------------------------------------------------
__global__ __launch_bounds__(256) void prep(
    const float* __restrict__ x, const float* __restrict__ Wq,
    const float* __restrict__ Wk, const float* __restrict__ Wv,
    const float* __restrict__ Wo, unsigned short* __restrict__ xb,
    unsigned short* __restrict__ wqkv_t, unsigned short* __restrict__ wo_t) {
  const int z = blockIdx.z;
  if (z == 4) {
    const int bid = blockIdx.y * 32 + blockIdx.x;  // 0..1023
    const size_t i0 = ((size_t)bid * 256 + threadIdx.x) * 16;
#pragma unroll
    for (int half = 0; half < 2; ++half) {
      const size_t o = i0 + half * 8;
      float4 a = *(const float4*)(x + o);
      float4 b = *(const float4*)(x + o + 4);
      union { unsigned int d[4]; short8 v; } t;
      t.d[0] = cvtpk(a.x, a.y); t.d[1] = cvtpk(a.z, a.w);
      t.d[2] = cvtpk(b.x, b.y); t.d[3] = cvtpk(b.z, b.w);
      *(short8*)(xb + o) = t.v;
    }
    return;
  }
  const float* W = (z == 0) ? Wq : (z == 1) ? Wk : (z == 2) ? Wv : Wo;
  unsigned short* out = (z < 3) ? (wqkv_t + (size_t)z * 1024 * 1024) : wo_t;

  __shared__ float T[32][33];
  const int r = threadIdx.x >> 3;
  const int c4 = (threadIdx.x & 7) << 2;
  const int k0 = blockIdx.x * 32, n0 = blockIdx.y * 32;

  float4 v = *(const float4*)(W + (size_t)(k0 + r) * 1024 + n0 + c4);
  T[r][c4 + 0] = v.x; T[r][c4 + 1] = v.y; T[r][c4 + 2] = v.z; T[r][c4 + 3] = v.w;
  __syncthreads();

  union { unsigned short u[4]; short4v v4; } o;
#pragma unroll
  for (int i = 0; i < 4; ++i) o.u[i] = f2bf(T[c4 + i][r]);
  *(short4v*)(out + (size_t)(n0 + r) * 1024 + k0 + c4) = o.v4;
}

// ---------------------------------------------------------------------------
// bf16 MFMA GEMM core, 128x128x64 tile, XOR-swizzled LDS staging, double-
// buffered with COUNTED vmcnt (T4): stage(t+1) is issued before compute(t)
// and only the PREVIOUS tile's 8 loads are waited on (vmcnt(8)), so the
// prefetch stays in flight across the whole compute phase + both barriers.
// Raw s_barrier (not __syncthreads) so the compiler can't re-drain vmcnt(0).
// S layout: [buf][A 8192 | B 8192] shorts, 64 KB total.
// ---------------------------------------------------------------------------
__device__ __forceinline__ void stage_tile(
    const unsigned short* __restrict__ A, const unsigned short* __restrict__ Bt,
    unsigned short* S, int buf, int bm, int bn, int k0, int wave, int lane) {
  unsigned short* As = S + buf * 16384;
  unsigned short* Bs = As + 8192;
#pragma unroll
  for (int t = 0; t < 4; ++t) {
    const int c = (wave * 4 + t) * 64 + lane;
    const int srow = c >> 3;
    const int sgc = ((c & 7) ^ (srow & 7)) * 8;
    async_copy16(As + (size_t)c * 8, A + (size_t)(bm + srow) * GK + k0 + sgc);
  }
#pragma unroll
  for (int t = 0; t < 4; ++t) {
    const int c = (wave * 4 + t) * 64 + lane;
    const int srow = c >> 3;
    const int sgc = ((c & 7) ^ (srow & 7)) * 8;
    async_copy16(Bs + (size_t)c * 8, Bt + (size_t)(bn + srow) * GK + k0 + sgc);
  }
}

__device__ __forceinline__ void gemm_core(
    const unsigned short* __restrict__ A, const unsigned short* __restrict__ Bt,
    unsigned short* S, int bm, int bn, float4v acc[4][4]) {
  const int tid = threadIdx.x;
  const int wave = tid >> 6, lane = tid & 63;
  const int quad = lane >> 4, l16 = lane & 15;
  const int wr = wave >> 1, wc = wave & 1;
  const int sw = l16 & 7;

  // prologue: stage tile 0 into buf 0
  stage_tile(A, Bt, S, 0, bm, bn, 0, wave, lane);

  for (int t = 0; t < NT_K; ++t) {
    if (t + 1 < NT_K) {
      // issue next-tile loads (8 per wave) into the other buffer, then wait
      // for the PREVIOUS 8 only: prefetch remains in flight during compute.
      stage_tile(A, Bt, S, (t + 1) & 1, bm, bn, (t + 1) * 64, wave, lane);
      asm volatile("s_waitcnt vmcnt(8)" ::: "memory");
    } else {
      asm volatile("s_waitcnt vmcnt(0)" ::: "memory");
    }
    __builtin_amdgcn_sched_barrier(0);
    __builtin_amdgcn_s_barrier();  // buf[t] resident for all waves
    __builtin_amdgcn_sched_barrier(0);

    const unsigned short* Asc = S + (t & 1) * 16384;
    const unsigned short* Bsc = Asc + 8192;
#pragma unroll
    for (int h = 0; h < 2; ++h) {
      short8 af[4], bfr[4];
#pragma unroll
      for (int i = 0; i < 4; ++i) {
        const int row = wr * 64 + i * 16 + l16;
        af[i] = *(const short8*)&Asc[((size_t)row * 8 + ((h * 4 + quad) ^ sw)) * 8];
      }
#pragma unroll
      for (int j = 0; j < 4; ++j) {
        const int row = wc * 64 + j * 16 + l16;
        bfr[j] = *(const short8*)&Bsc[((size_t)row * 8 + ((h * 4 + quad) ^ sw)) * 8];
      }
#pragma unroll
      for (int i = 0; i < 4; ++i)
#pragma unroll
        for (int j = 0; j < 4; ++j)
          acc[i][j] = __builtin_amdgcn_mfma_f32_16x16x32_bf16(af[i], bfr[j], acc[i][j], 0, 0, 0);
    }

    __builtin_amdgcn_sched_barrier(0);
    __builtin_amdgcn_s_barrier();  // all waves done reading buf[t]
    __builtin_amdgcn_sched_barrier(0);
  }
}

// QKV GEMM: N = 3072 (Wq|Wk|Wv). Q pre-scaled by 0.125*log2(e), bhsd.
// XCD-chunked block swizzle: same-bn blocks share one XCD -> B-panels go
// L2-resident. Epilogue routes C through LDS for fully-coalesced stores.
__global__ __launch_bounds__(256) void gemm_qkv(
    const unsigned short* __restrict__ A, const unsigned short* __restrict__ Bt,
    const float* __restrict__ bq, const float* __restrict__ bk,
    const float* __restrict__ bv,
    unsigned short* __restrict__ qbuf, unsigned short* __restrict__ kblk,
    unsigned short* __restrict__ vblk) {
  // staging dbuf (32768 shorts) time-shares with epilogue C-tile (17408).
  __shared__ unsigned short SMEM[2 * 128 * 64 * 2];
  const int tid = threadIdx.x;
  const int wave = tid >> 6, lane = tid & 63;
  const int quad = lane >> 4, l16 = lane & 15;
  const int wr = wave >> 1, wc = wave & 1;

  // XCD-chunked swizzle: 768 blocks, 96 per XCD (768 % 8 == 0 -> bijective)
  const int lid = blockIdx.y * 32 + blockIdx.x;
  const int nid = (lid & 7) * 96 + (lid >> 3);
  const int bm = (nid & 31) * 128, bn = (nid >> 5) * 128;

  float4v acc[4][4] = {};
  gemm_core(A, Bt, SMEM, bm, bn, acc);

  __syncthreads();  // staging reads done (also vmcnt/lgkm drained) -> reuse LDS

  const int seg = bn >> 10;        // 0=Q 1=K 2=V (block fully inside one seg)
  const int nb0 = bn & 1023;
  const float* bias = (seg == 0) ? bq : (seg == 1) ? bk : bv;
  const float scale = (seg == 0) ? 0.18033688011112043f : 1.0f;  // 0.125*log2e

  // C fragments -> LDS [m][n], stride 136 shorts.
#pragma unroll
  for (int j = 0; j < 4; ++j) {
    const int nl = wc * 64 + j * 16 + l16;
    const float bsv = bias[nb0 + nl];
#pragma unroll
    for (int i = 0; i < 4; ++i) {
#pragma unroll
      for (int r = 0; r < 4; ++r) {
        const int ml = wr * 64 + i * 16 + quad * 4 + r;
        SMEM[ml * 136 + nl] = f2bf((acc[i][j][r] + bsv) * scale);
      }
    }
  }
  __syncthreads();

  const int b = bm >> 11;       // batch (block fully inside one batch)
  const int s0 = bm & 2047;     // seq base

  if (seg == 0) {
    // qbuf[(bh*SEQ+s)*64 + d]
#pragma unroll
    for (int it = 0; it < 8; ++it) {
      const int linear = it * 256 + tid;
      const int d3 = linear & 7;              // d-octet
      const int sl = (linear >> 3) & 127;     // local seq row
      const int h = linear >> 10;             // head within block (0..1)
      const short8 vv = *(const short8*)&SMEM[sl * 136 + h * 64 + d3 * 8];
      const int bh = b * NUM_HEADS + (nb0 >> 6) + h;
      *(short8*)&qbuf[((size_t)bh * SEQ + s0 + sl) * HEAD_DIM + d3 * 8] = vv;
    }
  } else if (seg == 1) {
    // kblk tile idx: f*512 + hb*256 + key*8 + d0  (f=d>>4, hb=(d>>3)&1)
#pragma unroll
    for (int it = 0; it < 8; ++it) {
      const int linear = it * 256 + tid;
      const int key = linear & 31;
      const int hb = (linear >> 5) & 1;
      const int f = (linear >> 6) & 3;
      const int st = (linear >> 8) & 3;       // 32-key sub-tile within block
      const int h = linear >> 10;
      const int ml = st * 32 + key;
      const int nl = h * 64 + f * 16 + hb * 8;
      const short8 vv = *(const short8*)&SMEM[ml * 136 + nl];
      const int bh = b * NUM_HEADS + (nb0 >> 6) + h;
      const int stg = (s0 >> 5) + st;
      *(short8*)&kblk[((size_t)bh * 64 + stg) * 2048 + f * 512 + hb * 256 + key * 8] = vv;
    }
  } else {
    // vblk tile idx: (kk*2+dt)*512 + s8*256 + d31*8 + s0i
#pragma unroll
    for (int it = 0; it < 8; ++it) {
      const int linear = it * 256 + tid;
      const int d31 = linear & 31;
      const int s8 = (linear >> 5) & 1;
      const int dt = (linear >> 6) & 1;
      const int kk = (linear >> 7) & 1;
      const int st = (linear >> 8) & 3;
      const int h = linear >> 10;
      const int nl = h * 64 + dt * 32 + d31;
      const int mlb = st * 32 + kk * 16 + s8 * 8;
      union { unsigned short u[8]; short8 v; } vv;
#pragma unroll
      for (int s0i = 0; s0i < 8; ++s0i)
        vv.u[s0i] = SMEM[(mlb + s0i) * 136 + nl];
      const int bh = b * NUM_HEADS + (nb0 >> 6) + h;
      const int stg = (s0 >> 5) + st;
      *(short8*)&vblk[((size_t)bh * 64 + stg) * 2048 + (kk * 2 + dt) * 512 +
                      s8 * 256 + d31 * 8] = vv.v;
    }
  }
}

// Output GEMM: N = 1024, fp32 out + bias. XCD swizzle: one bn-panel per XCD.
__global__ __launch_bounds__(256) void gemm_out(
    const unsigned short* __restrict__ A, const unsigned short* __restrict__ Bt,
    const float* __restrict__ bo, float* __restrict__ out) {
  __shared__ unsigned short S[2 * 128 * 64 * 2];
  const int wave = threadIdx.x >> 6, lane = threadIdx.x & 63;
  const int quad = lane >> 4, l16 = lane & 15;
  const int wr = wave >> 1, wc = wave & 1;

  // 256 blocks, 32 per XCD (bijective)
  const int lid = blockIdx.y * 32 + blockIdx.x;
  const int nid = (lid & 7) * 32 + (lid >> 3);
  const int bm = (nid & 31) * 128, bn = (nid >> 5) * 128;

  float4v acc[4][4] = {};
  gemm_core(A, Bt, S, bm, bn, acc);

#pragma unroll
  for (int j = 0; j < 4; ++j) {
    const int n = bn + wc * 64 + j * 16 + l16;
    const float bsv = bo[n];
#pragma unroll
    for (int i = 0; i < 4; ++i) {
#pragma unroll
      for (int r = 0; r < 4; ++r) {
        const int m = bm + wr * 64 + i * 16 + quad * 4 + r;
        out[(size_t)m * D_OUT + n] = acc[i][j][r] + bsv;
      }
    }
  }
}

// ---------------------------------------------------------------------------
// Flash attention, in-block split-K-4, swapped-QK^T 32x32 MFMA with fully
// in-register softmax (T12): mfma(K,Q) puts each lane's 16 P values on its
// own q-row (col=lane&31); cvt_pk_bf16 pairs + permlane32_swap redistribute
// keys into the PV A-fragment layout. No P LDS round-trip, no per-step DS
// traffic. Fixed-max exp2 partials are addable across waves; end-of-kernel
// in-LDS combine (single __syncthreads).
// ---------------------------------------------------------------------------
#define OBS 72  // OB row stride (shorts): 16B-aligned, bank-spread

__global__ __launch_bounds__(256) void attn_kernel(
    const unsigned short* __restrict__ qf, const unsigned short* __restrict__ kblk,
    const unsigned short* __restrict__ vblk, unsigned short* __restrict__ ctx) {
  __shared__ unsigned short OB[4 * 32 * OBS];  // per-wave partial O (18 KB)
  __shared__ float LL[4 * 32];                 // per-wave partial l

  const int id = blockIdx.x;
  const int bh = id & 31;                 // low bits -> XCD spread
  const int qblk = 63 - (id >> 5);        // long q-blocks first
  const int qw0 = qblk * 32;
  const int tid = threadIdx.x;
  const int w = tid >> 6;
  const int lane = tid & 63;
  const int l32 = lane & 31;
  const int hi = lane >> 5;

  const int nt = qblk + 1;                // total key tiles
  const int qch = (nt + 3) >> 2;
  const int t0 = w * qch;
  const int t1 = min(nt, t0 + qch);

  const size_t bh_base = (size_t)bh * SEQ * HEAD_DIM;
  const unsigned short* kb = kblk + bh_base + (size_t)lane * 8;
  const unsigned short* vb = vblk + bh_base + (size_t)lane * 8;

  // Q as 32x32x16 B-operand frags: col=lane&31=q-row, k=(lane>>5)*8+j
  short8 qfr[4];
  {
    const unsigned short* qrow =
        qf + bh_base + (size_t)(qw0 + l32) * HEAD_DIM + hi * 8;
#pragma unroll
    for (int f = 0; f < 4; ++f) qfr[f] = *(const short8*)(qrow + f * 16);
  }

  f32x16 O0 = {}, O1 = {};  // O[q = (reg&3)+8*(reg>>2)+4*hi][d = dt*32 + l32]
  float l_part = 0.f;

  if (t0 < t1) {
    short8 kA[4], vA[4], kB[4], vB[4];

    auto load = [&](int kt, short8 kd[4], short8 vd[4]) {
      const size_t base = (size_t)kt * 2048;
#pragma unroll
      for (int f = 0; f < 4; ++f) kd[f] = *(const short8*)(kb + base + f * 512);
#pragma unroll
      for (int f = 0; f < 4; ++f) vd[f] = *(const short8*)(vb + base + f * 512);
    };

    auto step = [&](int kt, const short8 kd[4], const short8 vd[4], bool masked) {
      (void)kt;
      // swapped QK^T: C[key = (reg&3)+8*(reg>>2)+4*hi][q = l32]
      f32x16 s = {};
#pragma unroll
      for (int f = 0; f < 4; ++f)
        s = __builtin_amdgcn_mfma_f32_32x32x16_bf16(kd[f], qfr[f], s, 0, 0, 0);

      float p[16];
#pragma unroll
      for (int g = 0; g < 4; ++g)
#pragma unroll
        for (int r = 0; r < 4; ++r) {
          float sv = s[g * 4 + r];
          if (masked) {
            const int krow = r + 8 * g + 4 * hi;  // diagonal tile: key<=q  <=>  krow<=l32
            sv = (krow <= l32) ? sv : -1e30f;
          }
          const float pv = __builtin_exp2f(sv);
          p[g * 4 + r] = pv;
          l_part += pv;
        }

      // c[g*2+t] holds keys {8g+4hi+2t, +1} for q=l32
      unsigned int c[8];
#pragma unroll
      for (int g = 0; g < 4; ++g) {
        c[g * 2 + 0] = cvtpk(p[g * 4 + 0], p[g * 4 + 1]);
        c[g * 2 + 1] = cvtpk(p[g * 4 + 2], p[g * 4 + 3]);
      }
      // permlane32_swap(a,b): a' = {a_lo, b_lo}, b' = {a_hi, b_hi}
      // pa[kk] dword t: keys kk*16 + hi*8 + {2t,2t+1}  (PV A-operand layout)
      {
        int2v r0 = __builtin_amdgcn_permlane32_swap((int)c[0], (int)c[2], false, false);
        c[0] = (unsigned int)r0.x; c[2] = (unsigned int)r0.y;
        int2v r1 = __builtin_amdgcn_permlane32_swap((int)c[1], (int)c[3], false, false);
        c[1] = (unsigned int)r1.x; c[3] = (unsigned int)r1.y;
        int2v r2 = __builtin_amdgcn_permlane32_swap((int)c[4], (int)c[6], false, false);
        c[4] = (unsigned int)r2.x; c[6] = (unsigned int)r2.y;
        int2v r3 = __builtin_amdgcn_permlane32_swap((int)c[5], (int)c[7], false, false);
        c[5] = (unsigned int)r3.x; c[7] = (unsigned int)r3.y;
      }
      union { unsigned int d[4]; short8 v; } pa0, pa1;
      pa0.d[0] = c[0]; pa0.d[1] = c[1]; pa0.d[2] = c[2]; pa0.d[3] = c[3];
      pa1.d[0] = c[4]; pa1.d[1] = c[5]; pa1.d[2] = c[6]; pa1.d[3] = c[7];

      // PV: O[dt] += pa[kk] x V[kk*2+dt]
      O0 = __builtin_amdgcn_mfma_f32_32x32x16_bf16(pa0.v, vd[0], O0, 0, 0, 0);
      O1 = __builtin_amdgcn_mfma_f32_32x32x16_bf16(pa0.v, vd[1], O1, 0, 0, 0);
      O0 = __builtin_amdgcn_mfma_f32_32x32x16_bf16(pa1.v, vd[2], O0, 0, 0, 0);
      O1 = __builtin_amdgcn_mfma_f32_32x32x16_bf16(pa1.v, vd[3], O1, 0, 0, 0);
    };

    load(t0, kA, vA);
    int kt = t0;
    while (true) {
      const bool lastA = (kt == t1 - 1);
      if (!lastA) load(kt + 1, kB, vB);
      step(kt, kA, vA, kt == nt - 1);
      if (lastA) break;
      ++kt;
      const bool lastB = (kt == t1 - 1);
      if (!lastB) load(kt + 1, kA, vA);
      step(kt, kB, vB, kt == nt - 1);
      if (lastB) break;
      ++kt;
    }
  }

  // ---- write this wave's partials to LDS ----
  // lane l and l+32 hold complementary keys of the same q-row
  const float lsum = l_part + __shfl_xor(l_part, 32);
  if (hi == 0) LL[w * 32 + l32] = lsum;
#pragma unroll
  for (int g = 0; g < 4; ++g)
#pragma unroll
    for (int r = 0; r < 4; ++r) {
      const int reg = g * 4 + r;
      const int row = r + 8 * g + 4 * hi;
      OB[(w * 32 + row) * OBS + l32] = f2bf(O0[reg]);
      OB[(w * 32 + row) * OBS + 32 + l32] = f2bf(O1[reg]);
    }

  __syncthreads();

  // ---- in-LDS combine: wave w handles rows w*8..w*8+7 ----
  const int row = w * 8 + (lane >> 3);
  const int col0 = (lane & 7) * 8;
  float acc[8] = {};
#pragma unroll
  for (int u = 0; u < 4; ++u) {
    const short8 t = *(const short8*)&OB[(u * 32 + row) * OBS + col0];
#pragma unroll
    for (int i = 0; i < 8; ++i) acc[i] += bf2f((unsigned short)t[i]);
  }
  const float inv = 1.0f / (LL[row] + LL[32 + row] + LL[64 + row] + LL[96 + row]);
  union { unsigned short u[8]; short8 v; } o;
#pragma unroll
  for (int i = 0; i < 8; ++i) o.u[i] = f2bf(acc[i] * inv);
  const int b = bh >> 4, h = bh & 15;
  const int qg = qw0 + row;
  *(short8*)(ctx + ((size_t)b * SEQ + qg) * D_OUT + h * HEAD_DIM + col0) = o.v;
}

// ---------------------------------------------------------------------------
extern "C" void kernel_launch(void* const* d_in, const int* in_sizes, int n_in,
                              void* d_out, int out_size, void* d_ws, size_t ws_size,
                              hipStream_t stream) {
  const float* x  = (const float*)d_in[0];
  const float* Wq = (const float*)d_in[1];
  const float* bq = (const float*)d_in[2];
  const float* Wk = (const float*)d_in[3];
  const float* bk = (const float*)d_in[4];
  const float* Wv = (const float*)d_in[5];
  const float* bv = (const float*)d_in[6];
  const float* Wo = (const float*)d_in[7];
  const float* bo = (const float*)d_in[8];
  float* out = (float*)d_out;

  const int M = BATCH * SEQ;  // 4096
  unsigned short* xb     = (unsigned short*)d_ws;                  // 8 MB
  unsigned short* wqkv_t = xb + (size_t)M * D_IN;                  // 6 MB
  unsigned short* wo_t   = wqkv_t + (size_t)3 * D_OUT * D_IN;      // 2 MB
  unsigned short* qb     = wo_t + (size_t)D_OUT * D_OUT;           // 8 MB
  unsigned short* kblk   = qb + (size_t)M * D_OUT;                 // 8 MB
  unsigned short* vblk   = kblk + (size_t)M * D_OUT;               // 8 MB
  unsigned short* cb     = vblk + (size_t)M * D_OUT;               // 8 MB

  prep<<<dim3(32, 32, 5), 256, 0, stream>>>(x, Wq, Wk, Wv, Wo, xb, wqkv_t, wo_t);
  gemm_qkv<<<dim3(M / 128, 3 * D_OUT / 128), 256, 0, stream>>>(
      xb, wqkv_t, bq, bk, bv, qb, kblk, vblk);
  attn_kernel<<<dim3(32 * 64), 256, 0, stream>>>(qb, kblk, vblk, cb);
  gemm_out<<<dim3(M / 128, D_OUT / 128), 256, 0, stream>>>(cb, wo_t, bo, out);
}

// Round 5
// 178.281 us; speedup vs baseline: 1.1510x; 1.0010x over previous
//
#include <hip/hip_runtime.h>
#include <cmath>

#define D_IN 1024
#define D_OUT 1024
#define NUM_HEADS 16
#define HEAD_DIM 64
#define BATCH 2
#define SEQ 2048
#define GK 1024
#define KT 32
#define NT_K (GK / 64)

typedef __attribute__((ext_vector_type(8))) short short8;
typedef __attribute__((ext_vector_type(4))) short short4v;
typedef __attribute__((ext_vector_type(4))) float float4v;
typedef __attribute__((ext_vector_type(16))) float f32x16;
typedef __attribute__((ext_vector_type(2))) int int2v;

__device__ __forceinline__ unsigned short f2bf(float f) {
  unsigned int u = __builtin_bit_cast(unsigned int, f);
  unsigned int r = (u + 0x7FFFu + ((u >> 16) & 1u)) >> 16;
  return (unsigned short)r;
}
__device__ __forceinline__ float bf2f(unsigned short h) {
  return __builtin_bit_cast(float, (unsigned int)h << 16);
}

// pack two f32 -> one dword of 2 bf16 (lo, hi), RNE
__device__ __forceinline__ unsigned int cvtpk(float lo, float hi) {
  unsigned int r;
  asm("v_cvt_pk_bf16_f32 %0, %1, %2" : "=v"(r) : "v"(lo), "v"(hi));
  return r;
}

// async global->LDS, 16 B per lane. lds base must be wave-uniform.
__device__ __forceinline__ void async_copy16(void* lds, const void* g) {
  __builtin_amdgcn_global_load_lds(
      (const __attribute__((address_space(1))) unsigned int*)g,
      (__attribute__((address_space(3))) unsigned int*)lds, 16, 0, 0);
}

// ---------------------------------------------------------------------------
// Fused pre-pass. z<4: transpose W (fp32 [K][N] -> bf16 [N][K]);
// z==4: convert x fp32 -> bf16 (16 elems/thread, cvt_pk packed).
// ---------------------------------------------------------------------------
__global__ __launch_bounds__(256) void prep(
    const float* __restrict__ x, const float* __restrict__ Wq,
    const float* __restrict__ Wk, const float* __restrict__ Wv,
    const float* __restrict__ Wo, unsigned short* __restrict__ xb,
    unsigned short* __restrict__ wqkv_t, unsigned short* __restrict__ wo_t) {
  const int z = blockIdx.z;
  if (z == 4) {
    const int bid = blockIdx.y * 32 + blockIdx.x;  // 0..1023
    const size_t i0 = ((size_t)bid * 256 + threadIdx.x) * 16;
#pragma unroll
    for (int half = 0; half < 2; ++half) {
      const size_t o = i0 + half * 8;
      float4 a = *(const float4*)(x + o);
      float4 b = *(const float4*)(x + o + 4);
      union { unsigned int d[4]; short8 v; } t;
      t.d[0] = cvtpk(a.x, a.y); t.d[1] = cvtpk(a.z, a.w);
      t.d[2] = cvtpk(b.x, b.y); t.d[3] = cvtpk(b.z, b.w);
      *(short8*)(xb + o) = t.v;
    }
    return;
  }
  const float* W = (z == 0) ? Wq : (z == 1) ? Wk : (z == 2) ? Wv : Wo;
  unsigned short* out = (z < 3) ? (wqkv_t + (size_t)z * 1024 * 1024) : wo_t;

  __shared__ float T[32][33];
  const int r = threadIdx.x >> 3;
  const int c4 = (threadIdx.x & 7) << 2;
  const int k0 = blockIdx.x * 32, n0 = blockIdx.y * 32;

  float4 v = *(const float4*)(W + (size_t)(k0 + r) * 1024 + n0 + c4);
  T[r][c4 + 0] = v.x; T[r][c4 + 1] = v.y; T[r][c4 + 2] = v.z; T[r][c4 + 3] = v.w;
  __syncthreads();

  union { unsigned short u[4]; short4v v4; } o;
#pragma unroll
  for (int i = 0; i < 4; ++i) o.u[i] = f2bf(T[c4 + i][r]);
  *(short4v*)(out + (size_t)(n0 + r) * 1024 + k0 + c4) = o.v4;
}

// ---------------------------------------------------------------------------
// bf16 MFMA GEMM core, 128x128x64 tile, XOR-swizzled LDS staging, double-
// buffered with COUNTED vmcnt (T4): stage(t+1) is issued before compute(t)
// and only the PREVIOUS tile's 8 loads are waited on (vmcnt(8)), so the
// prefetch stays in flight across the whole compute phase + both barriers.
// Raw s_barrier (not __syncthreads) so the compiler can't re-drain vmcnt(0).
// S layout: [buf][A 8192 | B 8192] shorts, 64 KB total.
// ---------------------------------------------------------------------------
__device__ __forceinline__ void stage_tile(
    const unsigned short* __restrict__ A, const unsigned short* __restrict__ Bt,
    unsigned short* S, int buf, int bm, int bn, int k0, int wave, int lane) {
  unsigned short* As = S + buf * 16384;
  unsigned short* Bs = As + 8192;
#pragma unroll
  for (int t = 0; t < 4; ++t) {
    const int c = (wave * 4 + t) * 64 + lane;
    const int srow = c >> 3;
    const int sgc = ((c & 7) ^ (srow & 7)) * 8;
    async_copy16(As + (size_t)c * 8, A + (size_t)(bm + srow) * GK + k0 + sgc);
  }
#pragma unroll
  for (int t = 0; t < 4; ++t) {
    const int c = (wave * 4 + t) * 64 + lane;
    const int srow = c >> 3;
    const int sgc = ((c & 7) ^ (srow & 7)) * 8;
    async_copy16(Bs + (size_t)c * 8, Bt + (size_t)(bn + srow) * GK + k0 + sgc);
  }
}

__device__ __forceinline__ void gemm_core(
    const unsigned short* __restrict__ A, const unsigned short* __restrict__ Bt,
    unsigned short* S, int bm, int bn, float4v acc[4][4]) {
  const int tid = threadIdx.x;
  const int wave = tid >> 6, lane = tid & 63;
  const int quad = lane >> 4, l16 = lane & 15;
  const int wr = wave >> 1, wc = wave & 1;
  const int sw = l16 & 7;

  // prologue: stage tile 0 into buf 0
  stage_tile(A, Bt, S, 0, bm, bn, 0, wave, lane);

  for (int t = 0; t < NT_K; ++t) {
    if (t + 1 < NT_K) {
      // issue next-tile loads (8 per wave) into the other buffer, then wait
      // for the PREVIOUS 8 only: prefetch remains in flight during compute.
      stage_tile(A, Bt, S, (t + 1) & 1, bm, bn, (t + 1) * 64, wave, lane);
      asm volatile("s_waitcnt vmcnt(8)" ::: "memory");
    } else {
      asm volatile("s_waitcnt vmcnt(0)" ::: "memory");
    }
    __builtin_amdgcn_sched_barrier(0);
    __builtin_amdgcn_s_barrier();  // buf[t] resident for all waves
    __builtin_amdgcn_sched_barrier(0);

    const unsigned short* Asc = S + (t & 1) * 16384;
    const unsigned short* Bsc = Asc + 8192;
#pragma unroll
    for (int h = 0; h < 2; ++h) {
      short8 af[4], bfr[4];
#pragma unroll
      for (int i = 0; i < 4; ++i) {
        const int row = wr * 64 + i * 16 + l16;
        af[i] = *(const short8*)&Asc[((size_t)row * 8 + ((h * 4 + quad) ^ sw)) * 8];
      }
#pragma unroll
      for (int j = 0; j < 4; ++j) {
        const int row = wc * 64 + j * 16 + l16;
        bfr[j] = *(const short8*)&Bsc[((size_t)row * 8 + ((h * 4 + quad) ^ sw)) * 8];
      }
#pragma unroll
      for (int i = 0; i < 4; ++i)
#pragma unroll
        for (int j = 0; j < 4; ++j)
          acc[i][j] = __builtin_amdgcn_mfma_f32_16x16x32_bf16(af[i], bfr[j], acc[i][j], 0, 0, 0);
    }

    __builtin_amdgcn_sched_barrier(0);
    __builtin_amdgcn_s_barrier();  // all waves done reading buf[t]
    __builtin_amdgcn_sched_barrier(0);
  }
}

// QKV GEMM: N = 3072 (Wq|Wk|Wv). Q pre-scaled by 0.125*log2(e), bhsd.
// XCD-chunked block swizzle: same-bn blocks share one XCD -> B-panels go
// L2-resident. Epilogue routes C through LDS for fully-coalesced stores.
__global__ __launch_bounds__(256) void gemm_qkv(
    const unsigned short* __restrict__ A, const unsigned short* __restrict__ Bt,
    const float* __restrict__ bq, const float* __restrict__ bk,
    const float* __restrict__ bv,
    unsigned short* __restrict__ qbuf, unsigned short* __restrict__ kblk,
    unsigned short* __restrict__ vblk) {
  // staging dbuf (32768 shorts) time-shares with epilogue C-tile (17408).
  __shared__ unsigned short SMEM[2 * 128 * 64 * 2];
  const int tid = threadIdx.x;
  const int wave = tid >> 6, lane = tid & 63;
  const int quad = lane >> 4, l16 = lane & 15;
  const int wr = wave >> 1, wc = wave & 1;

  // XCD-chunked swizzle: 768 blocks, 96 per XCD (768 % 8 == 0 -> bijective)
  const int lid = blockIdx.y * 32 + blockIdx.x;
  const int nid = (lid & 7) * 96 + (lid >> 3);
  const int bm = (nid & 31) * 128, bn = (nid >> 5) * 128;

  float4v acc[4][4] = {};
  gemm_core(A, Bt, SMEM, bm, bn, acc);

  __syncthreads();  // staging reads done (also vmcnt/lgkm drained) -> reuse LDS

  const int seg = bn >> 10;        // 0=Q 1=K 2=V (block fully inside one seg)
  const int nb0 = bn & 1023;
  const float* bias = (seg == 0) ? bq : (seg == 1) ? bk : bv;
  const float scale = (seg == 0) ? 0.18033688011112043f : 1.0f;  // 0.125*log2e

  // C fragments -> LDS [m][n], stride 136 shorts.
#pragma unroll
  for (int j = 0; j < 4; ++j) {
    const int nl = wc * 64 + j * 16 + l16;
    const float bsv = bias[nb0 + nl];
#pragma unroll
    for (int i = 0; i < 4; ++i) {
#pragma unroll
      for (int r = 0; r < 4; ++r) {
        const int ml = wr * 64 + i * 16 + quad * 4 + r;
        SMEM[ml * 136 + nl] = f2bf((acc[i][j][r] + bsv) * scale);
      }
    }
  }
  __syncthreads();

  const int b = bm >> 11;       // batch (block fully inside one batch)
  const int s0 = bm & 2047;     // seq base

  if (seg == 0) {
    // qbuf[(bh*SEQ+s)*64 + d]
#pragma unroll
    for (int it = 0; it < 8; ++it) {
      const int linear = it * 256 + tid;
      const int d3 = linear & 7;              // d-octet
      const int sl = (linear >> 3) & 127;     // local seq row
      const int h = linear >> 10;             // head within block (0..1)
      const short8 vv = *(const short8*)&SMEM[sl * 136 + h * 64 + d3 * 8];
      const int bh = b * NUM_HEADS + (nb0 >> 6) + h;
      *(short8*)&qbuf[((size_t)bh * SEQ + s0 + sl) * HEAD_DIM + d3 * 8] = vv;
    }
  } else if (seg == 1) {
    // kblk tile idx: f*512 + hb*256 + key*8 + d0  (f=d>>4, hb=(d>>3)&1)
#pragma unroll
    for (int it = 0; it < 8; ++it) {
      const int linear = it * 256 + tid;
      const int key = linear & 31;
      const int hb = (linear >> 5) & 1;
      const int f = (linear >> 6) & 3;
      const int st = (linear >> 8) & 3;       // 32-key sub-tile within block
      const int h = linear >> 10;
      const int ml = st * 32 + key;
      const int nl = h * 64 + f * 16 + hb * 8;
      const short8 vv = *(const short8*)&SMEM[ml * 136 + nl];
      const int bh = b * NUM_HEADS + (nb0 >> 6) + h;
      const int stg = (s0 >> 5) + st;
      *(short8*)&kblk[((size_t)bh * 64 + stg) * 2048 + f * 512 + hb * 256 + key * 8] = vv;
    }
  } else {
    // vblk tile idx: (kk*2+dt)*512 + s8*256 + d31*8 + s0i
#pragma unroll
    for (int it = 0; it < 8; ++it) {
      const int linear = it * 256 + tid;
      const int d31 = linear & 31;
      const int s8 = (linear >> 5) & 1;
      const int dt = (linear >> 6) & 1;
      const int kk = (linear >> 7) & 1;
      const int st = (linear >> 8) & 3;
      const int h = linear >> 10;
      const int nl = h * 64 + dt * 32 + d31;
      const int mlb = st * 32 + kk * 16 + s8 * 8;
      union { unsigned short u[8]; short8 v; } vv;
#pragma unroll
      for (int s0i = 0; s0i < 8; ++s0i)
        vv.u[s0i] = SMEM[(mlb + s0i) * 136 + nl];
      const int bh = b * NUM_HEADS + (nb0 >> 6) + h;
      const int stg = (s0 >> 5) + st;
      *(short8*)&vblk[((size_t)bh * 64 + stg) * 2048 + (kk * 2 + dt) * 512 +
                      s8 * 256 + d31 * 8] = vv.v;
    }
  }
}

// Output GEMM: N = 1024, fp32 out + bias. XCD swizzle: one bn-panel per XCD.
__global__ __launch_bounds__(256) void gemm_out(
    const unsigned short* __restrict__ A, const unsigned short* __restrict__ Bt,
    const float* __restrict__ bo, float* __restrict__ out) {
  __shared__ unsigned short S[2 * 128 * 64 * 2];
  const int wave = threadIdx.x >> 6, lane = threadIdx.x & 63;
  const int quad = lane >> 4, l16 = lane & 15;
  const int wr = wave >> 1, wc = wave & 1;

  // 256 blocks, 32 per XCD (bijective)
  const int lid = blockIdx.y * 32 + blockIdx.x;
  const int nid = (lid & 7) * 32 + (lid >> 3);
  const int bm = (nid & 31) * 128, bn = (nid >> 5) * 128;

  float4v acc[4][4] = {};
  gemm_core(A, Bt, S, bm, bn, acc);

#pragma unroll
  for (int j = 0; j < 4; ++j) {
    const int n = bn + wc * 64 + j * 16 + l16;
    const float bsv = bo[n];
#pragma unroll
    for (int i = 0; i < 4; ++i) {
#pragma unroll
      for (int r = 0; r < 4; ++r) {
        const int m = bm + wr * 64 + i * 16 + quad * 4 + r;
        out[(size_t)m * D_OUT + n] = acc[i][j][r] + bsv;
      }
    }
  }
}

// ---------------------------------------------------------------------------
// Flash attention, 64-row q-blocks with TWO q-tiles per wave sharing every
// K/V register load (halves L2 KV traffic vs 32-row blocks, doubles per-wave
// ILP). In-block split-K-4 (waves own disjoint key-tile ranges; fixed-max
// exp2 partials are addable), swapped-QK^T 32x32 MFMA, fully in-register
// softmax (T12): cvt_pk_bf16 + permlane32_swap redistribute P into the PV
// A-fragment layout. qt=0 skips the block's last key tile (fully masked);
// diagonal mask at tile 2j+qt. End-of-kernel in-LDS combine.
// ---------------------------------------------------------------------------
#define OBS 72  // OB row stride (shorts): 16B-aligned, bank-spread

__global__ __launch_bounds__(256) void attn_kernel(
    const unsigned short* __restrict__ qf, const unsigned short* __restrict__ kblk,
    const unsigned short* __restrict__ vblk, unsigned short* __restrict__ ctx) {
  __shared__ unsigned short OB[4 * 64 * OBS];  // per-wave partial O (36 KB)
  __shared__ float LL[4 * 64];                 // per-wave partial l

  const int id = blockIdx.x;
  const int bh = id & 31;                 // low bits -> XCD spread
  const int j = 31 - (id >> 5);           // 64-row q-block, long blocks first
  const int qw0 = j * 64;
  const int tid = threadIdx.x;
  const int w = tid >> 6;
  const int lane = tid & 63;
  const int l32 = lane & 31;
  const int hi = lane >> 5;

  const int nt = 2 * j + 2;               // total key tiles for this block
  const int qch = (nt + 3) >> 2;
  const int t0 = w * qch;
  const int t1 = min(nt, t0 + qch);

  const size_t bh_base = (size_t)bh * SEQ * HEAD_DIM;
  const unsigned short* kb = kblk + bh_base + (size_t)lane * 8;
  const unsigned short* vb = vblk + bh_base + (size_t)lane * 8;

  // Q as 32x32x16 B-operand frags: col=lane&31=q-row, k=(lane>>5)*8+jj
  short8 qfr[2][4];
#pragma unroll
  for (int qt = 0; qt < 2; ++qt) {
    const unsigned short* qrow =
        qf + bh_base + (size_t)(qw0 + qt * 32 + l32) * HEAD_DIM + hi * 8;
#pragma unroll
    for (int f = 0; f < 4; ++f) qfr[qt][f] = *(const short8*)(qrow + f * 16);
  }

  f32x16 O[2][2] = {};  // [qt][dt]; O[q = (reg&3)+8*(reg>>2)+4*hi][d = dt*32+l32]
  float l_part[2] = {};

  if (t0 < t1) {
    short8 kA[4], vA[4], kB[4], vB[4];

    auto load = [&](int kt, short8 kd[4], short8 vd[4]) {
      const size_t base = (size_t)kt * 2048;
#pragma unroll
      for (int f = 0; f < 4; ++f) kd[f] = *(const short8*)(kb + base + f * 512);
#pragma unroll
      for (int f = 0; f < 4; ++f) vd[f] = *(const short8*)(vb + base + f * 512);
    };

    auto step = [&](int kt, const short8 kd[4], const short8 vd[4]) {
#pragma unroll
      for (int qt = 0; qt < 2; ++qt) {
        if (qt == 0 && kt > 2 * j) continue;   // fully masked tile for qt=0
        const bool masked = (kt == 2 * j + qt);  // diagonal tile for this qt
        // swapped QK^T: C[key = (reg&3)+8*(reg>>2)+4*hi][q = l32]
        f32x16 s = {};
#pragma unroll
        for (int f = 0; f < 4; ++f)
          s = __builtin_amdgcn_mfma_f32_32x32x16_bf16(kd[f], qfr[qt][f], s, 0, 0, 0);

        float p[16];
#pragma unroll
        for (int g = 0; g < 4; ++g)
#pragma unroll
          for (int r = 0; r < 4; ++r) {
            float sv = s[g * 4 + r];
            if (masked) {
              const int krow = r + 8 * g + 4 * hi;  // key<=q  <=>  krow<=l32
              sv = (krow <= l32) ? sv : -1e30f;
            }
            const float pv = __builtin_exp2f(sv);
            p[g * 4 + r] = pv;
            l_part[qt] += pv;
          }

        // c[g*2+t] holds keys {8g+4hi+2t, +1} for q=l32
        unsigned int c[8];
#pragma unroll
        for (int g = 0; g < 4; ++g) {
          c[g * 2 + 0] = cvtpk(p[g * 4 + 0], p[g * 4 + 1]);
          c[g * 2 + 1] = cvtpk(p[g * 4 + 2], p[g * 4 + 3]);
        }
        // permlane32_swap(a,b): a' = {a_lo, b_lo}, b' = {a_hi, b_hi}
        // pa[kk] dword t: keys kk*16 + hi*8 + {2t,2t+1}  (PV A-operand layout)
        {
          int2v r0 = __builtin_amdgcn_permlane32_swap((int)c[0], (int)c[2], false, false);
          c[0] = (unsigned int)r0.x; c[2] = (unsigned int)r0.y;
          int2v r1 = __builtin_amdgcn_permlane32_swap((int)c[1], (int)c[3], false, false);
          c[1] = (unsigned int)r1.x; c[3] = (unsigned int)r1.y;
          int2v r2 = __builtin_amdgcn_permlane32_swap((int)c[4], (int)c[6], false, false);
          c[4] = (unsigned int)r2.x; c[6] = (unsigned int)r2.y;
          int2v r3 = __builtin_amdgcn_permlane32_swap((int)c[5], (int)c[7], false, false);
          c[5] = (unsigned int)r3.x; c[7] = (unsigned int)r3.y;
        }
        union { unsigned int d[4]; short8 v; } pa0, pa1;
        pa0.d[0] = c[0]; pa0.d[1] = c[1]; pa0.d[2] = c[2]; pa0.d[3] = c[3];
        pa1.d[0] = c[4]; pa1.d[1] = c[5]; pa1.d[2] = c[6]; pa1.d[3] = c[7];

        // PV: O[qt][dt] += pa[kk] x V[kk*2+dt]
        O[qt][0] = __builtin_amdgcn_mfma_f32_32x32x16_bf16(pa0.v, vd[0], O[qt][0], 0, 0, 0);
        O[qt][1] = __builtin_amdgcn_mfma_f32_32x32x16_bf16(pa0.v, vd[1], O[qt][1], 0, 0, 0);
        O[qt][0] = __builtin_amdgcn_mfma_f32_32x32x16_bf16(pa1.v, vd[2], O[qt][0], 0, 0, 0);
        O[qt][1] = __builtin_amdgcn_mfma_f32_32x32x16_bf16(pa1.v, vd[3], O[qt][1], 0, 0, 0);
      }
    };

    load(t0, kA, vA);
    int kt = t0;
    while (true) {
      const bool lastA = (kt == t1 - 1);
      if (!lastA) load(kt + 1, kB, vB);
      step(kt, kA, vA);
      if (lastA) break;
      ++kt;
      const bool lastB = (kt == t1 - 1);
      if (!lastB) load(kt + 1, kA, vA);
      step(kt, kB, vB);
      if (lastB) break;
      ++kt;
    }
  }

  // ---- write this wave's partials to LDS ----
  // lane l and l+32 hold complementary keys of the same q-row
#pragma unroll
  for (int qt = 0; qt < 2; ++qt) {
    const float lsum = l_part[qt] + __shfl_xor(l_part[qt], 32);
    if (hi == 0) LL[w * 64 + qt * 32 + l32] = lsum;
#pragma unroll
    for (int g = 0; g < 4; ++g)
#pragma unroll
      for (int r = 0; r < 4; ++r) {
        const int reg = g * 4 + r;
        const int row = qt * 32 + r + 8 * g + 4 * hi;
        OB[(w * 64 + row) * OBS + l32] = f2bf(O[qt][0][reg]);
        OB[(w * 64 + row) * OBS + 32 + l32] = f2bf(O[qt][1][reg]);
      }
  }

  __syncthreads();

  // ---- in-LDS combine: 512 row-chunks over 256 threads, 2 reps ----
  const int b = bh >> 4, h = bh & 15;
#pragma unroll
  for (int rep = 0; rep < 2; ++rep) {
    const int idx = rep * 256 + tid;
    const int row = idx >> 3;           // 0..63
    const int col0 = (idx & 7) * 8;
    float acc[8] = {};
#pragma unroll
    for (int u = 0; u < 4; ++u) {
      const short8 t = *(const short8*)&OB[(u * 64 + row) * OBS + col0];
#pragma unroll
      for (int i = 0; i < 8; ++i) acc[i] += bf2f((unsigned short)t[i]);
    }
    const float inv =
        1.0f / (LL[row] + LL[64 + row] + LL[128 + row] + LL[192 + row]);
    union { unsigned short u[8]; short8 v; } o;
#pragma unroll
    for (int i = 0; i < 8; ++i) o.u[i] = f2bf(acc[i] * inv);
    const int qg = qw0 + row;
    *(short8*)(ctx + ((size_t)b * SEQ + qg) * D_OUT + h * HEAD_DIM + col0) = o.v;
  }
}

// ---------------------------------------------------------------------------
extern "C" void kernel_launch(void* const* d_in, const int* in_sizes, int n_in,
                              void* d_out, int out_size, void* d_ws, size_t ws_size,
                              hipStream_t stream) {
  const float* x  = (const float*)d_in[0];
  const float* Wq = (const float*)d_in[1];
  const float* bq = (const float*)d_in[2];
  const float* Wk = (const float*)d_in[3];
  const float* bk = (const float*)d_in[4];
  const float* Wv = (const float*)d_in[5];
  const float* bv = (const float*)d_in[6];
  const float* Wo = (const float*)d_in[7];
  const float* bo = (const float*)d_in[8];
  float* out = (float*)d_out;

  const int M = BATCH * SEQ;  // 4096
  unsigned short* xb     = (unsigned short*)d_ws;                  // 8 MB
  unsigned short* wqkv_t = xb + (size_t)M * D_IN;                  // 6 MB
  unsigned short* wo_t   = wqkv_t + (size_t)3 * D_OUT * D_IN;      // 2 MB
  unsigned short* qb     = wo_t + (size_t)D_OUT * D_OUT;           // 8 MB
  unsigned short* kblk   = qb + (size_t)M * D_OUT;                 // 8 MB
  unsigned short* vblk   = kblk + (size_t)M * D_OUT;               // 8 MB
  unsigned short* cb     = vblk + (size_t)M * D_OUT;               // 8 MB

  prep<<<dim3(32, 32, 5), 256, 0, stream>>>(x, Wq, Wk, Wv, Wo, xb, wqkv_t, wo_t);
  gemm_qkv<<<dim3(M / 128, 3 * D_OUT / 128), 256, 0, stream>>>(
      xb, wqkv_t, bq, bk, bv, qb, kblk, vblk);
  attn_kernel<<<dim3(32 * 32), 256, 0, stream>>>(qb, kblk, vblk, cb);
  gemm_out<<<dim3(M / 128, D_OUT / 128), 256, 0, stream>>>(cb, wo_t, bo, out);
}